// Round 2
// baseline (1263.582 us; speedup 1.0000x reference)
//
#include <hip/hip_runtime.h>
#include <hip/hip_bf16.h>
#include <stdint.h>

typedef __attribute__((ext_vector_type(4))) float f32x4;
typedef __attribute__((ext_vector_type(8))) short s16x8;
typedef __attribute__((ext_vector_type(4))) short s16x4;

// XOR-swizzle of 16B-granule index within a row (involution on low 3 bits)
#define SWZ(g, row) ((((g) & ~7) | (((g) ^ ((row) & 7)) & 7)))

__device__ __forceinline__ unsigned short f2bf(float f) {
  unsigned u = __builtin_bit_cast(unsigned, f);
  u += 0x7fffu + ((u >> 16) & 1u);   // round-to-nearest-even
  return (unsigned short)(u >> 16);
}

__device__ __forceinline__ void gld16(const void* g, void* l) {
  __builtin_amdgcn_global_load_lds(
      (const __attribute__((address_space(1))) void*)g,
      (__attribute__((address_space(3))) void*)l, 16, 0, 0);
}

// ---------------------------------------------------------------- convert
__global__ void cvt_f32_to_bf16(const float* __restrict__ src,
                                unsigned short* __restrict__ dst, int n4) {
  int i = blockIdx.x * blockDim.x + threadIdx.x;
  if (i >= n4) return;
  float4 v = ((const float4*)src)[i];
  s16x4 o;
  o[0] = (short)f2bf(v.x); o[1] = (short)f2bf(v.y);
  o[2] = (short)f2bf(v.z); o[3] = (short)f2bf(v.w);
  ((s16x4*)dst)[i] = o;
}

// ---------------------------------------------------------------- GEMM C = A * Bt^T
template<int EPI>
__global__ __launch_bounds__(256) void gemm_bt(
    const unsigned short* __restrict__ A,
    const unsigned short* __restrict__ Bt,
    float* __restrict__ C, int N, int K,
    const float* __restrict__ cosT, const float* __restrict__ sinT,
    unsigned short* __restrict__ qOut, unsigned short* __restrict__ kOut,
    unsigned short* __restrict__ vtOut)
{
  __shared__ char smem[32768];
  const int tid = (int)threadIdx.x;
  const int w  = tid >> 6, l = tid & 63;
  const int lg = l & 15, hg = l >> 4;
  const int bn0 = (int)blockIdx.x * 128, bm0 = (int)blockIdx.y * 128;

  f32x4 acc[2][8] = {};
  const int nkt = K >> 6;
  for (int kt = 0; kt < nkt; ++kt) {
    __syncthreads();
    for (int i = 0; i < 4; ++i) {
      const int G = w * 256 + i * 64 + l;
      const int row = G >> 3, g = G & 7;
      const int gs = SWZ(g, row);
      gld16((const char*)(A  + (size_t)(bm0 + row) * K + (size_t)kt * 64) + (gs << 4),
            smem + w * 4096 + i * 1024);
      gld16((const char*)(Bt + (size_t)(bn0 + row) * K + (size_t)kt * 64) + (gs << 4),
            smem + 16384 + w * 4096 + i * 1024);
    }
    asm volatile("s_waitcnt vmcnt(0)" ::: "memory");
    __syncthreads();
    for (int ks = 0; ks < 2; ++ks) {
      s16x8 af[2], bfr[8];
      for (int ai = 0; ai < 2; ++ai) {
        const int ra = w * 32 + ai * 16 + lg;
        const int gr = SWZ(4 * ks + hg, ra);
        af[ai] = *(const s16x8*)(smem + ra * 128 + (gr << 4));
      }
      for (int bi = 0; bi < 8; ++bi) {
        const int rb = bi * 16 + lg;
        const int gr = SWZ(4 * ks + hg, rb);
        bfr[bi] = *(const s16x8*)(smem + 16384 + rb * 128 + (gr << 4));
      }
      for (int ai = 0; ai < 2; ++ai)
        for (int bi = 0; bi < 8; ++bi)
          acc[ai][bi] = __builtin_amdgcn_mfma_f32_16x16x32_bf16(
              af[ai], bfr[bi], acc[ai][bi], 0, 0, 0);
    }
  }

  if constexpr (EPI == 0) {
    for (int ai = 0; ai < 2; ++ai)
      for (int bi = 0; bi < 8; ++bi) {
        const int col  = bn0 + bi * 16 + lg;
        const int row0 = bm0 + w * 32 + ai * 16 + hg * 4;
        for (int r = 0; r < 4; ++r)
          C[(size_t)(row0 + r) * N + col] = acc[ai][bi][r];
      }
  } else {
    const int t = bn0 >> 11;
    const int h = (bn0 >> 7) & 15;
    if (t < 2) {
      unsigned short* dst = (t == 0) ? qOut : kOut;
      for (int ai = 0; ai < 2; ++ai)
        for (int bi = 0; bi < 4; ++bi)
          for (int r = 0; r < 4; ++r) {
            const int gr = bm0 + w * 32 + ai * 16 + hg * 4 + r;
            const int b = gr >> 11, s1 = gr & 2047;
            const int c0 = bi * 16 + lg;
            const float x1 = acc[ai][bi][r];
            const float x2 = acc[ai][bi + 4][r];
            const float cv = cosT[s1 * 64 + c0];
            const float sv = sinT[s1 * 64 + c0];
            const size_t base = ((((size_t)b * 16 + h) * 2048) + s1) * 128;
            dst[base + c0]      = f2bf(x1 * cv - x2 * sv);
            dst[base + c0 + 64] = f2bf(x2 * cv + x1 * sv);
          }
    } else {
      for (int ai = 0; ai < 2; ++ai)
        for (int bi = 0; bi < 8; ++bi) {
          const int gr0 = bm0 + w * 32 + ai * 16 + hg * 4;
          const int b = gr0 >> 11, s0 = gr0 & 2047;
          const int d = bi * 16 + lg;
          s16x4 pk;
          for (int r = 0; r < 4; ++r) pk[r] = (short)f2bf(acc[ai][bi][r]);
          *(s16x4*)(vtOut + ((((size_t)b * 16 + h) * 128) + d) * 2048 + s0) = pk;
        }
    }
  }
}

// ---------------------------------------------------------------- flash attention
// grid: 512 blocks = (bh=32) x (8 paired q-tiles). Block handles q-tiles
// qtA=pi and qtB=31-pi (balanced causal work: 33 tile-equivalents each).
// 4 waves x 16 q-rows per q-tile. Shared K/V staging, double-buffered,
// prefetch-before-compute. Swapped QK^T; diagonal-only masking; defer-max.
__global__ __launch_bounds__(256, 2) void attn_fwd(
    const unsigned short* __restrict__ Qp, const unsigned short* __restrict__ Kp,
    const unsigned short* __restrict__ Vt, unsigned short* __restrict__ AO)
{
  __shared__ char sK[2][16384];   // [64][128] bf16, swizzled granules
  __shared__ char sV[2][16384];   // [128][64] bf16 (Vt tile), swizzled
  __shared__ char sP[16384];      // per-wave: A region 2KB + B region 2KB

  const int tid = (int)threadIdx.x, w = tid >> 6, l = tid & 63;
  const int lg = l & 15, hg = l >> 4;
  // XCD-bijective swizzle: each XCD's 64 blocks cover 4 heads (K/V L2-resident)
  const int wg = ((int)blockIdx.x & 7) * 64 + ((int)blockIdx.x >> 3);
  const int pi = wg & 15, bh = wg >> 4;
  const int qtA = pi, qtB = 31 - pi;
  const size_t qkBase = (size_t)bh * 2048 * 128;
  const int qw0A = qtA * 64 + w * 16, qw0B = qtB * 64 + w * 16;
  const int qiA = qw0A + lg, qiB = qw0B + lg;

  char* const pbA = sP + w * 4096;
  char* const pbB = pbA + 2048;

  // Q fragments (B-operand): lane holds q-row (l&15), feature 32*ks + 8*hg
  s16x8 qfA[4], qfB[4];
  for (int ks = 0; ks < 4; ++ks) {
    qfA[ks] = *(const s16x8*)(Qp + qkBase + (size_t)(qw0A + lg) * 128 + ks * 32 + hg * 8);
    qfB[ks] = *(const s16x8*)(Qp + qkBase + (size_t)(qw0B + lg) * 128 + ks * 32 + hg * 8);
  }

  f32x4 aoA[8] = {}, aoB[8] = {};
  float mA = -1e30f, lA = 0.f, mB = -1e30f, lB = 0.f;
  const float SCALE = 0.08838834764831845f;      // 1/sqrt(128)
  const float L2E = 1.4426950408889634f;
  const float CS = SCALE * L2E;

  auto stage = [&](int kv0, int bb) {
    for (int i = 0; i < 4; ++i) {
      const int G = w * 256 + i * 64 + l;
      const int rk = G >> 4, gk = G & 15;
      gld16((const char*)(Kp + qkBase + (size_t)(kv0 + rk) * 128) + (SWZ(gk, rk) << 4),
            &sK[bb][w * 4096 + i * 1024]);
      const int rv = G >> 3, gv = G & 7;
      gld16((const char*)(Vt + qkBase + (size_t)rv * 2048 + kv0) + (SWZ(gv, rv) << 4),
            &sV[bb][w * 4096 + i * 1024]);
    }
  };

  stage(0, 0);
  asm volatile("s_waitcnt vmcnt(0)" ::: "memory");
  __syncthreads();

  for (int kv = 0; kv <= qtB; ++kv) {
    const int cur = kv & 1;
    const int kv0 = kv * 64;
    if (kv < qtB) stage(kv0 + 64, cur ^ 1);
    const bool aAct = (kv <= qtA);

    // ---- QK^T (swapped): K-frag loads shared between both q-tiles
    f32x4 sSA[4] = {}, sSB[4] = {};
    for (int ks = 0; ks < 4; ++ks) {
      s16x8 kfr[4];
      for (int kf = 0; kf < 4; ++kf) {
        const int row = kf * 16 + lg;
        kfr[kf] = *(const s16x8*)(&sK[cur][row * 256 + (SWZ(4 * ks + hg, row) << 4)]);
      }
      for (int kf = 0; kf < 4; ++kf)
        sSB[kf] = __builtin_amdgcn_mfma_f32_16x16x32_bf16(kfr[kf], qfB[ks], sSB[kf], 0, 0, 0);
      if (aAct)
        for (int kf = 0; kf < 4; ++kf)
          sSA[kf] = __builtin_amdgcn_mfma_f32_16x16x32_bf16(kfr[kf], qfA[ks], sSA[kf], 0, 0, 0);
    }

    // ---- online softmax (scale folded into exp2 fma; defer-max THR=8)
    auto smax = [&](f32x4 (&sS)[4], float& m, float& lr, f32x4 (&ao)[8],
                    int qi, bool masked, char* pb) {
      float raw[4][4];
      for (int kf = 0; kf < 4; ++kf)
        for (int r = 0; r < 4; ++r) raw[kf][r] = sS[kf][r];
      if (masked) {
        for (int kf = 0; kf < 4; ++kf)
          for (int r = 0; r < 4; ++r) {
            const int j = kv0 + kf * 16 + hg * 4 + r;
            if (j > qi) raw[kf][r] = -1e30f;
          }
      }
      float mt = -1e30f;
      for (int kf = 0; kf < 4; ++kf)
        for (int r = 0; r < 4; ++r) mt = fmaxf(mt, raw[kf][r]);
      mt = fmaxf(mt, __shfl_xor(mt, 16));
      mt = fmaxf(mt, __shfl_xor(mt, 32));
      mt *= SCALE;
      if (!__all(mt - m <= 8.0f)) {
        const float mnew = fmaxf(m, mt);
        const float alpha = exp2f((m - mnew) * L2E);
        float ar[4];
        for (int r = 0; r < 4; ++r) ar[r] = __shfl(alpha, hg * 4 + r);
        for (int f = 0; f < 8; ++f)
          for (int r = 0; r < 4; ++r) ao[f][r] *= ar[r];
        lr *= alpha;
        m = mnew;
      }
      const float mL = m * L2E;
      float ls = 0.f;
      for (int kf = 0; kf < 4; ++kf) {
        s16x4 pk;
        for (int r = 0; r < 4; ++r) {
          const float e = exp2f(raw[kf][r] * CS - mL);
          ls += e;
          pk[r] = (short)f2bf(e);
        }
        const int j0 = kf * 16 + hg * 4;
        *(s16x4*)(pb + lg * 128 + (SWZ(j0 >> 3, lg) << 4) + ((j0 * 2) & 15)) = pk;
      }
      ls += __shfl_xor(ls, 16);
      ls += __shfl_xor(ls, 32);
      lr += ls;
    };

    smax(sSB, mB, lB, aoB, qiB, kv == qtB, pbB);
    if (aAct) smax(sSA, mA, lA, aoA, qiA, kv == qtA, pbA);
    asm volatile("" ::: "memory");   // P writes precede P reads (same wave, in-order DS)

    // ---- PV: V-frag loads shared between both q-tiles
    for (int jc = 0; jc < 2; ++jc) {
      const int gp = SWZ(hg + 4 * jc, lg);
      s16x8 paB = *(const s16x8*)(pbB + lg * 128 + (gp << 4));
      s16x8 paA;
      if (aAct) paA = *(const s16x8*)(pbA + lg * 128 + (gp << 4));
      for (int f = 0; f < 8; ++f) {
        const int rv = f * 16 + lg;
        s16x8 vb = *(const s16x8*)(&sV[cur][rv * 128 + (SWZ(hg + 4 * jc, rv) << 4)]);
        aoB[f] = __builtin_amdgcn_mfma_f32_16x16x32_bf16(paB, vb, aoB[f], 0, 0, 0);
        if (aAct)
          aoA[f] = __builtin_amdgcn_mfma_f32_16x16x32_bf16(paA, vb, aoA[f], 0, 0, 0);
      }
    }

    asm volatile("s_waitcnt vmcnt(0)" ::: "memory");
    __syncthreads();
  }

  // ---- normalize + store AO[b*2048+s][h*128+d] bf16 (both q-tiles)
  const int b = bh >> 4, h = bh & 15;
  float liA[4], liB[4];
  for (int r = 0; r < 4; ++r) {
    liA[r] = 1.0f / __shfl(lA, hg * 4 + r);
    liB[r] = 1.0f / __shfl(lB, hg * 4 + r);
  }
  for (int f = 0; f < 8; ++f) {
    const int d = h * 128 + f * 16 + lg;
    for (int r = 0; r < 4; ++r) {
      const int srA = qw0A + hg * 4 + r;
      const int srB = qw0B + hg * 4 + r;
      AO[((size_t)(b * 2048 + srA)) * 2048 + d] = f2bf(aoA[f][r] * liA[r]);
      AO[((size_t)(b * 2048 + srB)) * 2048 + d] = f2bf(aoB[f][r] * liB[r]);
    }
  }
}

// ---------------------------------------------------------------- launch
extern "C" void kernel_launch(void* const* d_in, const int* in_sizes, int n_in,
                              void* d_out, int out_size, void* d_ws, size_t ws_size,
                              hipStream_t stream) {
  const float* x    = (const float*)d_in[0];
  const float* qkvw = (const float*)d_in[1];
  const float* ow   = (const float*)d_in[2];
  const float* cosT = (const float*)d_in[3];
  const float* sinT = (const float*)d_in[4];
  float* out = (float*)d_out;

  unsigned short* X16  = (unsigned short*)d_ws;        // 4096x2048
  unsigned short* W16  = X16  + (size_t)8388608;       // 6144x2048
  unsigned short* OW16 = W16  + (size_t)12582912;      // 2048x2048
  unsigned short* Qp   = OW16 + (size_t)4194304;       // [2][16][2048][128]
  unsigned short* Kp   = Qp   + (size_t)8388608;
  unsigned short* Vtp  = Kp   + (size_t)8388608;       // [2][16][128][2048]
  unsigned short* AO   = Vtp  + (size_t)8388608;       // 4096x2048

  cvt_f32_to_bf16<<<8192, 256, 0, stream>>>(x, X16, 2097152);
  cvt_f32_to_bf16<<<12288, 256, 0, stream>>>(qkvw, W16, 3145728);
  cvt_f32_to_bf16<<<4096, 256, 0, stream>>>(ow, OW16, 1048576);

  dim3 g1(48, 32);  // N=6144, M=4096
  gemm_bt<1><<<g1, 256, 0, stream>>>(X16, W16, nullptr, 6144, 2048,
                                     cosT, sinT, Qp, Kp, Vtp);

  attn_fwd<<<512, 256, 0, stream>>>(Qp, Kp, Vtp, AO);

  dim3 g2(16, 32);  // N=2048, M=4096
  gemm_bt<0><<<g2, 256, 0, stream>>>(AO, OW16, out, 2048, 2048,
                                     nullptr, nullptr, nullptr, nullptr, nullptr);
}

// Round 3
// 266.293 us; speedup vs baseline: 4.7451x; 4.7451x over previous
//
#include <hip/hip_runtime.h>
#include <hip/hip_bf16.h>
#include <stdint.h>

typedef __attribute__((ext_vector_type(4))) float f32x4;
typedef __attribute__((ext_vector_type(8))) short s16x8;
typedef __attribute__((ext_vector_type(4))) short s16x4;

// XOR-swizzle of 16B-granule index within a row (involution on low 3 bits)
#define SWZ(g, row) ((((g) & ~7) | (((g) ^ ((row) & 7)) & 7)))

__device__ __forceinline__ unsigned short f2bf(float f) {
  unsigned u = __builtin_bit_cast(unsigned, f);
  u += 0x7fffu + ((u >> 16) & 1u);   // round-to-nearest-even
  return (unsigned short)(u >> 16);
}

__device__ __forceinline__ void gld16(const void* g, void* l) {
  __builtin_amdgcn_global_load_lds(
      (const __attribute__((address_space(1))) void*)g,
      (__attribute__((address_space(3))) void*)l, 16, 0, 0);
}

// ---------------------------------------------------------------- convert
__global__ void cvt_f32_to_bf16(const float* __restrict__ src,
                                unsigned short* __restrict__ dst, int n4) {
  int i = blockIdx.x * blockDim.x + threadIdx.x;
  if (i >= n4) return;
  float4 v = ((const float4*)src)[i];
  s16x4 o;
  o[0] = (short)f2bf(v.x); o[1] = (short)f2bf(v.y);
  o[2] = (short)f2bf(v.z); o[3] = (short)f2bf(v.w);
  ((s16x4*)dst)[i] = o;
}

// ---------------------------------------------------------------- GEMM C = A * Bt^T
// A: M x K bf16 row-major, Bt: N x K bf16 row-major. 128x128 tile, BK=64.
template<int EPI>
__global__ __launch_bounds__(256) void gemm_bt(
    const unsigned short* __restrict__ A,
    const unsigned short* __restrict__ Bt,
    float* __restrict__ C, int N, int K,
    const float* __restrict__ cosT, const float* __restrict__ sinT,
    unsigned short* __restrict__ qOut, unsigned short* __restrict__ kOut,
    unsigned short* __restrict__ vtOut)
{
  __shared__ char smem[32768];
  const int tid = (int)threadIdx.x;
  const int w  = tid >> 6, l = tid & 63;
  const int lg = l & 15, hg = l >> 4;
  const int bn0 = (int)blockIdx.x * 128, bm0 = (int)blockIdx.y * 128;

  f32x4 acc[2][8] = {};
  const int nkt = K >> 6;
  for (int kt = 0; kt < nkt; ++kt) {
    __syncthreads();
    for (int i = 0; i < 4; ++i) {
      const int G = w * 256 + i * 64 + l;
      const int row = G >> 3, g = G & 7;
      const int gs = SWZ(g, row);
      gld16((const char*)(A  + (size_t)(bm0 + row) * K + (size_t)kt * 64) + (gs << 4),
            smem + w * 4096 + i * 1024);
      gld16((const char*)(Bt + (size_t)(bn0 + row) * K + (size_t)kt * 64) + (gs << 4),
            smem + 16384 + w * 4096 + i * 1024);
    }
    asm volatile("s_waitcnt vmcnt(0)" ::: "memory");
    __syncthreads();
    for (int ks = 0; ks < 2; ++ks) {
      s16x8 af[2], bfr[8];
      for (int ai = 0; ai < 2; ++ai) {
        const int ra = w * 32 + ai * 16 + lg;
        const int gr = SWZ(4 * ks + hg, ra);
        af[ai] = *(const s16x8*)(smem + ra * 128 + (gr << 4));
      }
      for (int bi = 0; bi < 8; ++bi) {
        const int rb = bi * 16 + lg;
        const int gr = SWZ(4 * ks + hg, rb);
        bfr[bi] = *(const s16x8*)(smem + 16384 + rb * 128 + (gr << 4));
      }
      for (int ai = 0; ai < 2; ++ai)
        for (int bi = 0; bi < 8; ++bi)
          acc[ai][bi] = __builtin_amdgcn_mfma_f32_16x16x32_bf16(
              af[ai], bfr[bi], acc[ai][bi], 0, 0, 0);
    }
  }

  if constexpr (EPI == 0) {
    for (int ai = 0; ai < 2; ++ai)
      for (int bi = 0; bi < 8; ++bi) {
        const int col  = bn0 + bi * 16 + lg;
        const int row0 = bm0 + w * 32 + ai * 16 + hg * 4;
        for (int r = 0; r < 4; ++r)
          C[(size_t)(row0 + r) * N + col] = acc[ai][bi][r];
      }
  } else {
    const int t = bn0 >> 11;
    const int h = (bn0 >> 7) & 15;
    if (t < 2) {
      unsigned short* dst = (t == 0) ? qOut : kOut;
      for (int ai = 0; ai < 2; ++ai)
        for (int bi = 0; bi < 4; ++bi)
          for (int r = 0; r < 4; ++r) {
            const int gr = bm0 + w * 32 + ai * 16 + hg * 4 + r;
            const int b = gr >> 11, s1 = gr & 2047;
            const int c0 = bi * 16 + lg;
            const float x1 = acc[ai][bi][r];
            const float x2 = acc[ai][bi + 4][r];
            const float cv = cosT[s1 * 64 + c0];
            const float sv = sinT[s1 * 64 + c0];
            const size_t base = ((((size_t)b * 16 + h) * 2048) + s1) * 128;
            dst[base + c0]      = f2bf(x1 * cv - x2 * sv);
            dst[base + c0 + 64] = f2bf(x2 * cv + x1 * sv);
          }
    } else {
      for (int ai = 0; ai < 2; ++ai)
        for (int bi = 0; bi < 8; ++bi) {
          const int gr0 = bm0 + w * 32 + ai * 16 + hg * 4;
          const int b = gr0 >> 11, s0 = gr0 & 2047;
          const int d = bi * 16 + lg;
          s16x4 pk;
          for (int r = 0; r < 4; ++r) pk[r] = (short)f2bf(acc[ai][bi][r]);
          *(s16x4*)(vtOut + ((((size_t)b * 16 + h) * 128) + d) * 2048 + s0) = pk;
        }
    }
  }
}

// ---------------------------------------------------------------- flash attention
// grid: 1024 blocks. Balanced mapping: dispatch places bids {b,b+256,b+512,b+768}
// on one CU (4 resident at 40KB LDS); give those qt = {j,31-j,8+j,23-j} so every
// CU owns exactly 66 KV-tile-units. bh = c&31 keeps 4 heads per XCD (L2-resident).
// 4 waves x 16 q-rows, KV tiles of 64, swapped QK^T (lane owns a P-row).
__global__ __launch_bounds__(256) void attn_fwd(
    const unsigned short* __restrict__ Qp, const unsigned short* __restrict__ Kp,
    const unsigned short* __restrict__ Vt, unsigned short* __restrict__ AO)
{
  __shared__ char sK[16384];   // [64][128] bf16, 16 granules/row, swizzled
  __shared__ char sV[16384];   // [128][64] bf16 (Vt tile), 8 granules/row, swizzled
  __shared__ char sP[8192];    // per-wave [16][64] bf16, swizzled

  const int tid = (int)threadIdx.x, w = tid >> 6, l = tid & 63;
  const int lg = l & 15, hg = l >> 4;
  const int bid = (int)blockIdx.x;
  const int p = bid >> 8, c = bid & 255;
  const int j = c >> 5, bh = c & 31;
  const int qt = (p == 0) ? j : (p == 1) ? 31 - j : (p == 2) ? 8 + j : 23 - j;
  const size_t qkBase = (size_t)bh * 2048 * 128;   // also Vt head base (128*2048)
  const int qw0 = qt * 64 + w * 16;
  const int qi = qw0 + lg;

  // Q fragments (B-operand): lane holds q-row (l&15), feature 32*ks + 8*hg
  s16x8 qf[4];
  for (int ks = 0; ks < 4; ++ks)
    qf[ks] = *(const s16x8*)(Qp + qkBase + (size_t)(qw0 + lg) * 128 + ks * 32 + hg * 8);

  f32x4 acc_o[8] = {};
  float mrun = -1e30f, lrun = 0.f;
  const float SCALE = 0.08838834764831845f;   // 1/sqrt(128)
  const float L2E = 1.4426950408889634f;
  const float CS = SCALE * L2E;

  const int nkv = qt + 1;
  for (int kv = 0; kv < nkv; ++kv) {
    const int kv0 = kv * 64;
    __syncthreads();
    for (int i = 0; i < 4; ++i) {
      const int G = w * 256 + i * 64 + l;
      const int rk = G >> 4, gk = G & 15;
      gld16((const char*)(Kp + qkBase + (size_t)(kv0 + rk) * 128) + (SWZ(gk, rk) << 4),
            sK + w * 4096 + i * 1024);
      const int rv = G >> 3, gv = G & 7;
      gld16((const char*)(Vt + qkBase + (size_t)rv * 2048 + kv0) + (SWZ(gv, rv) << 4),
            sV + w * 4096 + i * 1024);
    }
    asm volatile("s_waitcnt vmcnt(0)" ::: "memory");
    __syncthreads();

    // ---- QK^T (swapped): accs[kf] holds S^T frag: row=j (kv), col=i (q-row)
    f32x4 accs[4] = {};
    for (int ks = 0; ks < 4; ++ks)
      for (int kf = 0; kf < 4; ++kf) {
        const int row = kf * 16 + lg;
        const int g = SWZ(4 * ks + hg, row);
        s16x8 kfrag = *(const s16x8*)(sK + row * 256 + (g << 4));
        accs[kf] = __builtin_amdgcn_mfma_f32_16x16x32_bf16(kfrag, qf[ks], accs[kf], 0, 0, 0);
      }

    // ---- online softmax (diag-only mask, folded scale, defer-max THR=8)
    const bool diag = (kv == qt);
    float raw[4][4];
    float mt = -1e30f;
    #pragma unroll
    for (int kf = 0; kf < 4; ++kf)
      #pragma unroll
      for (int r = 0; r < 4; ++r) {
        float s = accs[kf][r];
        if (diag) {
          const int jj = kv0 + kf * 16 + hg * 4 + r;
          s = (jj > qi) ? -1e30f : s;
        }
        raw[kf][r] = s;
        mt = fmaxf(mt, s);
      }
    mt = fmaxf(mt, __shfl_xor(mt, 16));
    mt = fmaxf(mt, __shfl_xor(mt, 32));
    mt *= SCALE;
    if (!__all(mt - mrun <= 8.0f)) {
      const float mnew = fmaxf(mrun, mt);
      const float alpha = exp2f((mrun - mnew) * L2E);
      float ar[4];
      #pragma unroll
      for (int r = 0; r < 4; ++r) ar[r] = __shfl(alpha, hg * 4 + r);
      #pragma unroll
      for (int f = 0; f < 8; ++f)
        #pragma unroll
        for (int r = 0; r < 4; ++r) acc_o[f][r] *= ar[r];
      lrun *= alpha;
      mrun = mnew;
    }
    const float mL = mrun * L2E;
    float ls = 0.f;
    char* pw = sP + w * 2048;
    #pragma unroll
    for (int kf = 0; kf < 4; ++kf) {
      s16x4 pk;
      #pragma unroll
      for (int r = 0; r < 4; ++r) {
        const float e = exp2f(raw[kf][r] * CS - mL);
        ls += e;
        pk[r] = (short)f2bf(e);
      }
      const int j0 = kf * 16 + hg * 4;
      *(s16x4*)(pw + lg * 128 + (SWZ(j0 >> 3, lg) << 4) + ((j0 * 2) & 15)) = pk;
    }
    ls += __shfl_xor(ls, 16);
    ls += __shfl_xor(ls, 32);
    lrun += ls;
    asm volatile("" ::: "memory");   // keep P writes before P reads (in-order DS)

    // ---- PV: O[i][d] += P[i][j] * Vt[d][j]
    for (int jc = 0; jc < 2; ++jc) {
      const int gp = SWZ(hg + 4 * jc, lg);
      s16x8 pa = *(const s16x8*)(pw + lg * 128 + (gp << 4));
      for (int f = 0; f < 8; ++f) {
        const int rv = f * 16 + lg;
        const int gv = SWZ(hg + 4 * jc, rv);
        s16x8 vb = *(const s16x8*)(sV + rv * 128 + (gv << 4));
        acc_o[f] = __builtin_amdgcn_mfma_f32_16x16x32_bf16(pa, vb, acc_o[f], 0, 0, 0);
      }
    }
  }

  // ---- normalize + store AO[b*2048+s][h*128+d] bf16
  float linv[4];
  for (int r = 0; r < 4; ++r) linv[r] = 1.0f / __shfl(lrun, hg * 4 + r);
  const int b = bh >> 4, h = bh & 15;
  for (int f = 0; f < 8; ++f) {
    const int d = h * 128 + f * 16 + lg;
    for (int r = 0; r < 4; ++r) {
      const int srow = qw0 + hg * 4 + r;
      AO[((size_t)(b * 2048 + srow)) * 2048 + d] = f2bf(acc_o[f][r] * linv[r]);
    }
  }
}

// ---------------------------------------------------------------- launch
extern "C" void kernel_launch(void* const* d_in, const int* in_sizes, int n_in,
                              void* d_out, int out_size, void* d_ws, size_t ws_size,
                              hipStream_t stream) {
  const float* x    = (const float*)d_in[0];
  const float* qkvw = (const float*)d_in[1];
  const float* ow   = (const float*)d_in[2];
  const float* cosT = (const float*)d_in[3];
  const float* sinT = (const float*)d_in[4];
  float* out = (float*)d_out;

  unsigned short* X16  = (unsigned short*)d_ws;        // 4096x2048
  unsigned short* W16  = X16  + (size_t)8388608;       // 6144x2048
  unsigned short* OW16 = W16  + (size_t)12582912;      // 2048x2048
  unsigned short* Qp   = OW16 + (size_t)4194304;       // [2][16][2048][128]
  unsigned short* Kp   = Qp   + (size_t)8388608;
  unsigned short* Vtp  = Kp   + (size_t)8388608;       // [2][16][128][2048]
  unsigned short* AO   = Vtp  + (size_t)8388608;       // 4096x2048

  cvt_f32_to_bf16<<<8192, 256, 0, stream>>>(x, X16, 2097152);
  cvt_f32_to_bf16<<<12288, 256, 0, stream>>>(qkvw, W16, 3145728);
  cvt_f32_to_bf16<<<4096, 256, 0, stream>>>(ow, OW16, 1048576);

  dim3 g1(48, 32);  // N=6144, M=4096
  gemm_bt<1><<<g1, 256, 0, stream>>>(X16, W16, nullptr, 6144, 2048,
                                     cosT, sinT, Qp, Kp, Vtp);

  attn_fwd<<<1024, 256, 0, stream>>>(Qp, Kp, Vtp, AO);

  dim3 g2(16, 32);  // N=2048, M=4096
  gemm_bt<0><<<g2, 256, 0, stream>>>(AO, OW16, out, 2048, 2048,
                                     nullptr, nullptr, nullptr, nullptr, nullptr);
}